// Round 7
// baseline (238.943 us; speedup 1.0000x reference)
//
#include <hip/hip_runtime.h>

typedef unsigned short u16;
typedef unsigned int u32;

typedef __bf16 bf16x8 __attribute__((ext_vector_type(8)));
typedef float floatx4 __attribute__((ext_vector_type(4)));

__device__ __forceinline__ u16 f2bf(float f) {
    union { float f; u32 u; } c; c.f = f;
    u32 u = c.u;
    u32 r = u + 0x7FFFu + ((u >> 16) & 1u);   // round-to-nearest-even
    return (u16)(r >> 16);
}
__device__ __forceinline__ float bf2f(u16 x) {
    union { u32 u; float f; } c; c.u = ((u32)x) << 16; return c.f;
}

// online-softmax partial combine: (M,P0,P1) += (m,p0,p1)
__device__ __forceinline__ void comb(float& M, float& P0, float& P1,
                                     float m, float p0, float p1) {
    float nm = fmaxf(M, m);
    float s = __expf(M - nm), t = __expf(m - nm);
    P0 = P0 * s + p0 * t;
    P1 = P1 * s + p1 * t;
    M = nm;
}

// async global(per-lane addr) -> LDS(wave-uniform base, HW adds lane*16B)
__device__ __forceinline__ void gload16(const void* g, void* l) {
    __builtin_amdgcn_global_load_lds(
        (const __attribute__((address_space(1))) void*)g,
        (__attribute__((address_space(3))) void*)l, 16, 0, 0);
}

// ---------------------------------------------------------------------------
// presplit: f32 features -> bf16 hi/lo arrays in MFMA-FRAGMENT-MAJOR layout:
//   offset(r,k) = ((r>>4)*16 + (k>>5))*512 + (((k>>3)&3)*16 + (r&15))*8 + (k&7)
// so a wave's fragment load is one coalesced 16B/lane access.
// First 16 x-blocks also gather taur/tauc; block (0,0) zeroes the ctrl block
// (arrival counter, ticket, 6 float accumulators) for this iteration.
// ---------------------------------------------------------------------------
__global__ __launch_bounds__(256) void presplit(
    const float* __restrict__ a, const float* __restrict__ b,
    u16* __restrict__ Ah, u16* __restrict__ Al,
    u16* __restrict__ Bh, u16* __restrict__ Bl, int n,
    const float* __restrict__ tauI, const float* __restrict__ tauT,
    const int* __restrict__ img_ids, const int* __restrict__ txt_ids,
    float* __restrict__ taur, float* __restrict__ tauc,
    u32* __restrict__ ctrl) {
    if (blockIdx.y == 0 && blockIdx.x == 0 && threadIdx.x < 8)
        ctrl[threadIdx.x] = 0u;
    if (blockIdx.y == 0 && blockIdx.x < 16) {
        int t = blockIdx.x * 256 + threadIdx.x;   // 0..4095
        taur[t] = tauI[img_ids[t]];
        tauc[t] = tauT[txt_ids[t]];
    }
    const float* src = blockIdx.y ? b : a;
    u16* dh = blockIdx.y ? Bh : Ah;
    u16* dl = blockIdx.y ? Bl : Al;
    int i = (blockIdx.x * 256 + threadIdx.x) * 8;
    if (i >= n) return;
    float4 v0 = *(const float4*)&src[i];
    float4 v1 = *(const float4*)&src[i + 4];
    float xs[8] = {v0.x, v0.y, v0.z, v0.w, v1.x, v1.y, v1.z, v1.w};
    u16 h[8], l[8];
#pragma unroll
    for (int e = 0; e < 8; e++) {
        h[e] = f2bf(xs[e]);
        l[e] = f2bf(xs[e] - bf2f(h[e]));
    }
    int r = i >> 9, k = i & 511;
    int off = (((r >> 4) << 4) + (k >> 5)) * 512 + ((((k >> 3) & 3) << 4) + (r & 15)) * 8;
    *(uint4*)&dh[off] = *(uint4*)h;
    *(uint4*)&dl[off] = *(uint4*)l;
}

// ---------------------------------------------------------------------------
// FUSED flash-GEMM + state copy + rows_final + scalars (2-launch pipeline).
// GEMM part = round-4 structure verbatim (68us, best measured): 256x256 tile,
// 8 waves (2M x 4N), 1 block/CU, LDS double-buffered (2 x 64KB), per BK=32
// slice: STAGE(next) -> copy-load -> 24 ds_read_b128 + 96 MFMA -> copy-store
// -> __syncthreads. Phase-split schedules measured SLOWER here (r5: 96us,
// r6: 104us -- phase bodies too thin for K=512's 16 slices).
// Tail fusion: after epilogue, threadfence + arrival atomicAdd; blocks >=16
// exit; blocks 0-15 (their CUs are idle -- grid == CU count) spin until all
// 256 arrived, then 8192 threads run the per-row state update, block-reduce
// the 6 scalar sums, atomicAdd into ctrl accs; last ticket writes out[0..4].
// RULE-#20: all acc indices compile-time.
// ---------------------------------------------------------------------------
__global__ __launch_bounds__(512, 2) void gemm_flash(
    const u16* __restrict__ Ah, const u16* __restrict__ Al,
    const u16* __restrict__ Bh, const u16* __restrict__ Bl,
    const float* __restrict__ taur, const float* __restrict__ tauc,
    float* __restrict__ rowpart, float* __restrict__ colpart,
    float* __restrict__ diag,
    const float* __restrict__ p0, const float* __restrict__ p1,
    const float* __restrict__ p2, const float* __restrict__ p3,
    const float* __restrict__ p4, const float* __restrict__ p5,
    const float* __restrict__ p6, const float* __restrict__ p7,
    float* __restrict__ out, long long n,
    const int* __restrict__ img_ids, const int* __restrict__ txt_ids,
    const int* __restrict__ epoch_p, u32* __restrict__ ctrl) {
    __shared__ u16 tiles[65536];     // 2 x 32768 u16 (2 x 64KB slice buffers)

    const int bid  = blockIdx.x;
    const int tid  = threadIdx.x;
    const int wave = tid >> 6, lane = tid & 63;
    const int lr = lane & 15, quad = lane >> 4;
    const int waveM = wave >> 2, waveN = wave & 3;   // 2 x 4 wave grid
    // XCD-aware swizzle: x = XCD (bid%8), s = slot. XCD x owns an 8x4 region.
    const int x = bid & 7, s = bid >> 3;
    const int rowtile = (x >> 2) * 8 + (s >> 2);     // 0..15
    const int coltile = (x & 3) * 4 + (s & 3);       // 0..15
    const int rowBase = rowtile * 256;
    const int colBase = coltile * 256;

    // staging role: wave w stages fragments f = w*8 + j (j=0..7)
    const int sa = wave >> 1;
    const u16* gb = (sa == 0) ? Ah : (sa == 1) ? Al : (sa == 2) ? Bh : Bl;
    const int base16 = ((sa < 2) ? rowBase : colBase) >> 4;
    const int jb = (wave & 1) * 8;

#define STAGE(slice, bufb)                                                    \
    {                                                                         \
        _Pragma("unroll")                                                     \
        for (int j = 0; j < 8; j++) {                                         \
            size_t ge = ((size_t)(base16 + jb + j)) * 8192 +                  \
                        (size_t)(slice) * 512 + lane * 8;                     \
            gload16(gb + ge, &tiles[(bufb) + (wave * 8 + j) * 512]);          \
        }                                                                     \
    }

    floatx4 acc[8][4];
#pragma unroll
    for (int mi = 0; mi < 8; mi++)
#pragma unroll
        for (int ni = 0; ni < 4; ni++) acc[mi][ni] = (floatx4)0.0f;

    const int Gq = (int)((n - 3) >> 2);
    const int ni32 = (int)n;
    float* dst5 = out + 5;

    // prologue: stage slice 0 into buffer 0
    STAGE(0, 0)

    // head+tail of the 8 state arrays (tiny): block 0 only
    if (bid == 0 && tid < 32) {
        int arr = tid >> 2, j = tid & 3;
        const float* sp = (arr & 4) ? ((arr & 2) ? ((arr & 1) ? p7 : p6) : ((arr & 1) ? p5 : p4))
                                    : ((arr & 2) ? ((arr & 1) ? p3 : p2) : ((arr & 1) ? p1 : p0));
        float* dp = dst5 + (size_t)arr * (size_t)n;
        long long tail0 = 3 + 4 * (long long)Gq;
        if (j < 3) dp[j] = sp[j];
        else
            for (long long z = tail0; z < n; z++) dp[z] = sp[z];
    }
    __syncthreads();   // buffer 0 ready

#pragma unroll 1
    for (int t = 0; t < 16; t++) {
        const int cb = (t & 1) << 15;        // current buffer (u16 offset)
        const int nb = cb ^ 32768;           // next buffer
        if (t < 15) STAGE(t + 1, nb)

        // fused state-copy: loads issued here, in flight under the MFMAs
        bool docopy = false;
        float c0 = 0.f, c1 = 0.f, c2 = 0.f, c3 = 0.f;
        int cdst = 0;
        {
            int c = bid * 512 + tid + t * 131072;
            int ck = c >> 18;
            int g = c & 262143;
            if (g < Gq) {
                docopy = true;
                int ce = 3 + 4 * g;
                cdst = ck * ni32 + ce;
                const float* sp = (ck & 4) ? ((ck & 2) ? ((ck & 1) ? p7 : p6) : ((ck & 1) ? p5 : p4))
                                           : ((ck & 2) ? ((ck & 1) ? p3 : p2) : ((ck & 1) ? p1 : p0));
                c0 = sp[ce]; c1 = sp[ce + 1]; c2 = sp[ce + 2]; c3 = sp[ce + 3];
            }
        }

        // compute slice t from current buffer (single pass; acc in AGPRs)
        {
            const int ab = cb + lane * 8;
            bf16x8 bh[4], bl[4];
#pragma unroll
            for (int ni = 0; ni < 4; ni++) {
                bh[ni] = *(const bf16x8*)&tiles[ab + (32 + waveN * 4 + ni) * 512];
                bl[ni] = *(const bf16x8*)&tiles[ab + (48 + waveN * 4 + ni) * 512];
            }
#pragma unroll
            for (int mi = 0; mi < 8; mi++) {
                bf16x8 ah = *(const bf16x8*)&tiles[ab + (waveM * 8 + mi) * 512];
                bf16x8 al = *(const bf16x8*)&tiles[ab + (16 + waveM * 8 + mi) * 512];
#pragma unroll
                for (int ni = 0; ni < 4; ni++) {
                    acc[mi][ni] = __builtin_amdgcn_mfma_f32_16x16x32_bf16(ah, bh[ni], acc[mi][ni], 0, 0, 0);
                    acc[mi][ni] = __builtin_amdgcn_mfma_f32_16x16x32_bf16(ah, bl[ni], acc[mi][ni], 0, 0, 0);
                    acc[mi][ni] = __builtin_amdgcn_mfma_f32_16x16x32_bf16(al, bh[ni], acc[mi][ni], 0, 0, 0);
                }
            }
        }

        if (docopy) {
            float4 q = {c0, c1, c2, c3};
            *(float4*)&dst5[cdst] = q;
        }
        __syncthreads();   // stage(t+1) landed + all reads of cb done
    }
#undef STAGE

    // --- epilogue ---
    // C/D layout: v(rr,cc): rr = rowBase+waveM*128+mi*16+quad*4+r,
    //                       cc = colBase+waveN*64+ni*16+lr   [m89/m91]
    float* redbuf = (float*)tiles;   // rows [0,3072), cols [3072,4608)

    // diagonal capture (raw sim value). STATIC acc indices, runtime predicate.
    if (rowtile == coltile) {
#pragma unroll
        for (int mi = 0; mi < 8; mi++)
#pragma unroll
            for (int ni = 0; ni < 4; ni++) {
                if (waveM * 128 + mi * 16 != waveN * 64 + ni * 16) continue;
#pragma unroll
                for (int r = 0; r < 4; r++)
                    if (lr == quad * 4 + r)
                        diag[colBase + waveN * 64 + ni * 16 + lr] = acc[mi][ni][r];
            }
    }

    // row partials: max-first, then one exp per element
#pragma unroll
    for (int mi = 0; mi < 8; mi++) {
#pragma unroll
        for (int r = 0; r < 4; r++) {
            int row_local = waveM * 128 + mi * 16 + quad * 4 + r;
            float vmax = fmaxf(fmaxf(acc[mi][0][r], acc[mi][1][r]),
                               fmaxf(acc[mi][2][r], acc[mi][3][r]));
#pragma unroll
            for (int mask = 1; mask <= 8; mask <<= 1)
                vmax = fmaxf(vmax, __shfl_xor(vmax, mask));
            float it = 1.0f / taur[rowBase + row_local];
            float M = vmax * it;
            float P0 = 0.f, P1 = 0.f;
#pragma unroll
            for (int ni = 0; ni < 4; ni++) {
                float y = acc[mi][ni][r] * it;
                float e = __expf(y - M);
                P0 += e;
                P1 += y * e;
            }
#pragma unroll
            for (int mask = 1; mask <= 8; mask <<= 1) {
                P0 += __shfl_xor(P0, mask);
                P1 += __shfl_xor(P1, mask);
            }
            if (lr == 0) {
                int xx = (row_local * 4 + waveN) * 3;
                redbuf[xx] = M; redbuf[xx + 1] = P0; redbuf[xx + 2] = P1;
            }
        }
    }

    // col partials: max-first, then one exp per element
#pragma unroll
    for (int ni = 0; ni < 4; ni++) {
        int col_local = waveN * 64 + ni * 16 + lr;
        float vmax = -3.4e38f;
#pragma unroll
        for (int mi = 0; mi < 8; mi++)
            vmax = fmaxf(vmax,
                fmaxf(fmaxf(acc[mi][ni][0], acc[mi][ni][1]),
                      fmaxf(acc[mi][ni][2], acc[mi][ni][3])));
#pragma unroll
        for (int mask = 16; mask <= 32; mask <<= 1)
            vmax = fmaxf(vmax, __shfl_xor(vmax, mask));
        float it = 1.0f / tauc[colBase + col_local];
        float M = vmax * it;
        float P0 = 0.f, P1 = 0.f;
#pragma unroll
        for (int mi = 0; mi < 8; mi++)
#pragma unroll
            for (int r = 0; r < 4; r++) {
                float y = acc[mi][ni][r] * it;
                float e = __expf(y - M);
                P0 += e;
                P1 += y * e;
            }
#pragma unroll
        for (int mask = 16; mask <= 32; mask <<= 1) {
            P0 += __shfl_xor(P0, mask);
            P1 += __shfl_xor(P1, mask);
        }
        if (quad == 0) {
            int xx = 3072 + (col_local * 2 + waveM) * 3;
            redbuf[xx] = M; redbuf[xx + 1] = P0; redbuf[xx + 2] = P1;
        }
    }
    __syncthreads();

    if (tid < 256) {
        int xx = tid * 12;
        float M = redbuf[xx], P0 = redbuf[xx + 1], P1 = redbuf[xx + 2];
        comb(M, P0, P1, redbuf[xx + 3], redbuf[xx + 4], redbuf[xx + 5]);
        comb(M, P0, P1, redbuf[xx + 6], redbuf[xx + 7], redbuf[xx + 8]);
        comb(M, P0, P1, redbuf[xx + 9], redbuf[xx + 10], redbuf[xx + 11]);
        float* dst = &rowpart[(size_t)(rowBase + tid) * 48 + coltile * 3];
        dst[0] = M; dst[1] = P0; dst[2] = P1;
    } else {
        int c = tid - 256;
        int xx = 3072 + c * 6;
        float M = redbuf[xx], P0 = redbuf[xx + 1], P1 = redbuf[xx + 2];
        comb(M, P0, P1, redbuf[xx + 3], redbuf[xx + 4], redbuf[xx + 5]);
        float* dst = &colpart[(size_t)(colBase + c) * 48 + rowtile * 3];
        dst[0] = M; dst[1] = P0; dst[2] = P1;
    }

    // ---------------- fused rows_final + scalars tail ----------------
    __threadfence();   // rowpart/colpart/diag/copy visible device-wide
    if (tid == 0)
        __hip_atomic_fetch_add(&ctrl[0], 1u, __ATOMIC_RELEASE,
                               __HIP_MEMORY_SCOPE_AGENT);
    if (bid >= 16) return;   // these 16 blocks' CUs are idle now (grid==CUs)

    if (tid == 0) {
        while (__hip_atomic_load(&ctrl[0], __ATOMIC_ACQUIRE,
                                 __HIP_MEMORY_SCOPE_AGENT) < 256u)
            __builtin_amdgcn_s_sleep(2);
    }
    __syncthreads();
    // per-thread acquire so every lane's subsequent loads see all blocks' data
    (void)__hip_atomic_load(&ctrl[0], __ATOMIC_ACQUIRE, __HIP_MEMORY_SCOPE_AGENT);

    {
        const int t = bid * 512 + tid;       // 0..8191
        const int side = t >> 12, i = t & 4095;
        const float* part = side ? colpart : rowpart;
        const int*   ids  = side ? txt_ids : img_ids;
        const float* s_in = side ? p1 : p0;
        const float* b_in = side ? p3 : p2;
        const float* u_in = side ? p5 : p4;

        const int id = ids[i];
        const float dg  = diag[i];
        const float tau = side ? tauc[i] : taur[i];

        const float4* pq = (const float4*)(part + (size_t)i * 48);
        float v[48];
#pragma unroll
        for (int k = 0; k < 12; k++) {
            float4 q = pq[k];
            v[4 * k] = q.x; v[4 * k + 1] = q.y;
            v[4 * k + 2] = q.z; v[4 * k + 3] = q.w;
        }
        float M = -3.4e38f, P0 = 0.f, P1 = 0.f;
#pragma unroll
        for (int k = 0; k < 16; k++)
            comb(M, P0, P1, v[3 * k], v[3 * k + 1], v[3 * k + 2]);

        const float old_b = b_in[id];
        const float old_s = s_in[id];
        const float old_u = u_in[id];
        const float y_ii  = dg / tau;

        float b_row = fmaxf(M - y_ii, old_b);
        float e  = expf(M - y_ii - b_row);
        float S0 = P0 * e - expf(-b_row);           // mask diagonal term
        float S1 = (P1 - y_ii * P0) * e;            // diagonal contributes 0

        float g = S0;
        float sI = (*epoch_p == 0) ? g
                 : 0.2f * old_s * expf(old_b - b_row) + 0.8f * g;
        float denom = sI + 1e-10f;
        float wsum = S1 / denom;
        float lossr = tau * wsum;
        float tw = logf(sI * (1.0f / 4095.0f)) + b_row + 8.0f - wsum;
        tw = fminf(fmaxf(tw, -5.0f), 5.0f);
        float uval = 0.5f * old_u + 0.5f * tw;
        float taun = fminf(fmaxf(tau - 1e-5f * uval, 0.005f), 0.05f);

        float* sect = out + 5;
        sect[(size_t)(0 + side) * (size_t)n + id] = sI;
        sect[(size_t)(2 + side) * (size_t)n + id] = b_row;
        sect[(size_t)(4 + side) * (size_t)n + id] = uval;
        sect[(size_t)(6 + side) * (size_t)n + id] = taun;

        // block-reduce {lossr, tw, tau} (whole block is one side: side=bid>>3)
        float r0 = lossr, r1 = tw, r2 = tau;
#pragma unroll
        for (int o = 32; o > 0; o >>= 1) {
            r0 += __shfl_xor(r0, o);
            r1 += __shfl_xor(r1, o);
            r2 += __shfl_xor(r2, o);
        }
        __syncthreads();               // redbuf free for reuse
        if (lane == 0) {
            redbuf[wave * 3 + 0] = r0;
            redbuf[wave * 3 + 1] = r1;
            redbuf[wave * 3 + 2] = r2;
        }
        __syncthreads();
        if (tid == 0) {
            float t0 = 0.f, t1 = 0.f, t2 = 0.f;
#pragma unroll
            for (int w = 0; w < 8; w++) {
                t0 += redbuf[w * 3 + 0];
                t1 += redbuf[w * 3 + 1];
                t2 += redbuf[w * 3 + 2];
            }
            float* accs = (float*)(ctrl + 2);   // [loss,tw,tau] x {I,T}
            __hip_atomic_fetch_add(&accs[side * 3 + 0], t0, __ATOMIC_RELAXED,
                                   __HIP_MEMORY_SCOPE_AGENT);
            __hip_atomic_fetch_add(&accs[side * 3 + 1], t1, __ATOMIC_RELAXED,
                                   __HIP_MEMORY_SCOPE_AGENT);
            __hip_atomic_fetch_add(&accs[side * 3 + 2], t2, __ATOMIC_RELAXED,
                                   __HIP_MEMORY_SCOPE_AGENT);
            __threadfence();
            u32 tk = __hip_atomic_fetch_add(&ctrl[1], 1u, __ATOMIC_ACQ_REL,
                                            __HIP_MEMORY_SCOPE_AGENT);
            if (tk == 15u) {
                float a0 = __hip_atomic_load(&accs[0], __ATOMIC_ACQUIRE, __HIP_MEMORY_SCOPE_AGENT);
                float a1 = __hip_atomic_load(&accs[1], __ATOMIC_ACQUIRE, __HIP_MEMORY_SCOPE_AGENT);
                float a2 = __hip_atomic_load(&accs[2], __ATOMIC_ACQUIRE, __HIP_MEMORY_SCOPE_AGENT);
                float a3 = __hip_atomic_load(&accs[3], __ATOMIC_ACQUIRE, __HIP_MEMORY_SCOPE_AGENT);
                float a4 = __hip_atomic_load(&accs[4], __ATOMIC_ACQUIRE, __HIP_MEMORY_SCOPE_AGENT);
                float a5 = __hip_atomic_load(&accs[5], __ATOMIC_ACQUIRE, __HIP_MEMORY_SCOPE_AGENT);
                const float inv = 1.0f / 4096.0f;
                out[0] = (a0 + a3) * inv;   // total loss
                out[1] = a2 * inv;          // tau_img mean
                out[2] = a5 * inv;          // tau_txt mean
                out[3] = a1 * inv;          // tw_i mean
                out[4] = a4 * inv;          // tw_t mean
            }
        }
    }
}

extern "C" void kernel_launch(void* const* d_in, const int* in_sizes, int n_in,
                              void* d_out, int out_size, void* d_ws, size_t ws_size,
                              hipStream_t stream) {
    const float* img   = (const float*)d_in[0];
    const float* txt   = (const float*)d_in[1];
    const float* s_I   = (const float*)d_in[2];
    const float* s_T   = (const float*)d_in[3];
    const float* b_I   = (const float*)d_in[4];
    const float* b_T   = (const float*)d_in[5];
    const float* u_I   = (const float*)d_in[6];
    const float* u_T   = (const float*)d_in[7];
    const float* tau_I = (const float*)d_in[8];
    const float* tau_T = (const float*)d_in[9];
    const int* image_ids = (const int*)d_in[10];
    const int* text_ids  = (const int*)d_in[11];
    const int* epoch     = (const int*)d_in[12];
    float* out = (float*)d_out;
    const long long n = in_sizes[2];   // 1,000,000
    const int nfeat = in_sizes[0];     // 4096*512

    const size_t MB = 1024 * 1024;
    // ws layout (< 24MB):
    //  [0,16MB): fragment-major splits Ah/Al/Bh/Bl
    //  16MB: rowpart 4096x16x3 f32 | 18MB: colpart | 20MB: diag
    //  20.25MB: taur | 20.5MB: tauc | 22MB: ctrl (2 u32 + 6 f32)
    u16* Ah = (u16*)d_ws;
    u16* Al = Ah + (size_t)nfeat;
    u16* Bh = Al + (size_t)nfeat;
    u16* Bl = Bh + (size_t)nfeat;
    float* rowpart = (float*)((char*)d_ws + 16 * MB);
    float* colpart = (float*)((char*)d_ws + 18 * MB);
    float* diag    = (float*)((char*)d_ws + 20 * MB);
    float* taur    = (float*)((char*)d_ws + 20 * MB + 256 * 1024);
    float* tauc    = (float*)((char*)d_ws + 20 * MB + 512 * 1024);
    u32*   ctrl    = (u32*)((char*)d_ws + 22 * MB);

    presplit<<<dim3((nfeat / 8 + 255) / 256, 2), 256, 0, stream>>>(
        img, txt, Ah, Al, Bh, Bl, nfeat,
        tau_I, tau_T, image_ids, text_ids, taur, tauc, ctrl);

    gemm_flash<<<256, 512, 0, stream>>>(
        Ah, Al, Bh, Bl, taur, tauc, rowpart, colpart, diag,
        s_I, s_T, b_I, b_T, u_I, u_T, tau_I, tau_T, out, n,
        image_ids, text_ids, epoch, ctrl);
}

// Round 8
// 171.740 us; speedup vs baseline: 1.3913x; 1.3913x over previous
//
#include <hip/hip_runtime.h>

typedef unsigned short u16;
typedef unsigned int u32;

typedef __bf16 bf16x8 __attribute__((ext_vector_type(8)));
typedef float floatx4 __attribute__((ext_vector_type(4)));

__device__ __forceinline__ u16 f2bf(float f) {
    union { float f; u32 u; } c; c.f = f;
    u32 u = c.u;
    u32 r = u + 0x7FFFu + ((u >> 16) & 1u);   // round-to-nearest-even
    return (u16)(r >> 16);
}
__device__ __forceinline__ float bf2f(u16 x) {
    union { u32 u; float f; } c; c.u = ((u32)x) << 16; return c.f;
}

// online-softmax partial combine: (M,P0,P1) += (m,p0,p1)
__device__ __forceinline__ void comb(float& M, float& P0, float& P1,
                                     float m, float p0, float p1) {
    float nm = fmaxf(M, m);
    float s = __expf(M - nm), t = __expf(m - nm);
    P0 = P0 * s + p0 * t;
    P1 = P1 * s + p1 * t;
    M = nm;
}

// async global(per-lane addr) -> LDS(wave-uniform base, HW adds lane*16B)
__device__ __forceinline__ void gload16(const void* g, void* l) {
    __builtin_amdgcn_global_load_lds(
        (const __attribute__((address_space(1))) void*)g,
        (__attribute__((address_space(3))) void*)l, 16, 0, 0);
}

// ---------------------------------------------------------------------------
// presplit: f32 features -> bf16 hi/lo arrays in MFMA-FRAGMENT-MAJOR layout:
//   offset(r,k) = ((r>>4)*16 + (k>>5))*512 + (((k>>3)&3)*16 + (r&15))*8 + (k&7)
// so a wave's fragment load is one coalesced 16B/lane access.
// First 16 x-blocks also gather taur/tauc; block (0,0) zeroes the ctrl words
// (6 float accumulators + ticket) for this iteration (graph-replay safe).
// ---------------------------------------------------------------------------
__global__ __launch_bounds__(256) void presplit(
    const float* __restrict__ a, const float* __restrict__ b,
    u16* __restrict__ Ah, u16* __restrict__ Al,
    u16* __restrict__ Bh, u16* __restrict__ Bl, int n,
    const float* __restrict__ tauI, const float* __restrict__ tauT,
    const int* __restrict__ img_ids, const int* __restrict__ txt_ids,
    float* __restrict__ taur, float* __restrict__ tauc,
    u32* __restrict__ ctrl) {
    if (blockIdx.y == 0 && blockIdx.x == 0 && threadIdx.x < 8)
        ctrl[threadIdx.x] = 0u;
    if (blockIdx.y == 0 && blockIdx.x < 16) {
        int t = blockIdx.x * 256 + threadIdx.x;   // 0..4095
        taur[t] = tauI[img_ids[t]];
        tauc[t] = tauT[txt_ids[t]];
    }
    const float* src = blockIdx.y ? b : a;
    u16* dh = blockIdx.y ? Bh : Ah;
    u16* dl = blockIdx.y ? Bl : Al;
    int i = (blockIdx.x * 256 + threadIdx.x) * 8;
    if (i >= n) return;
    float4 v0 = *(const float4*)&src[i];
    float4 v1 = *(const float4*)&src[i + 4];
    float xs[8] = {v0.x, v0.y, v0.z, v0.w, v1.x, v1.y, v1.z, v1.w};
    u16 h[8], l[8];
#pragma unroll
    for (int e = 0; e < 8; e++) {
        h[e] = f2bf(xs[e]);
        l[e] = f2bf(xs[e] - bf2f(h[e]));
    }
    int r = i >> 9, k = i & 511;
    int off = (((r >> 4) << 4) + (k >> 5)) * 512 + ((((k >> 3) & 3) << 4) + (r & 15)) * 8;
    *(uint4*)&dh[off] = *(uint4*)h;
    *(uint4*)&dl[off] = *(uint4*)l;
}

// ---------------------------------------------------------------------------
// FUSED flash-GEMM + state copy -- ROUND-4 STRUCTURE VERBATIM (best: 68us).
// 256x256 tile, 8 waves (2M x 4N), 1 block/CU, LDS double-buffered (2x64KB).
// Per BK=32 slice: STAGE(next) -> copy-load -> 24 ds_read_b128 + 96 MFMA ->
// copy-store -> __syncthreads.
// Measured dead ends (do not revisit): phase-split K-loops (r5 ring: 96us,
// r6 6-phase: 104us -- fetch-BW-bound, not schedule-bound); cross-block tail
// fusion (r7: +71us from 256 per-block L2-writeback release fences).
// RULE-#20: every acc index compile-time (runtime index -> 1.1GB scratch).
// ---------------------------------------------------------------------------
__global__ __launch_bounds__(512, 2) void gemm_flash(
    const u16* __restrict__ Ah, const u16* __restrict__ Al,
    const u16* __restrict__ Bh, const u16* __restrict__ Bl,
    const float* __restrict__ taur, const float* __restrict__ tauc,
    float* __restrict__ rowpart, float* __restrict__ colpart,
    float* __restrict__ diag,
    const float* __restrict__ p0, const float* __restrict__ p1,
    const float* __restrict__ p2, const float* __restrict__ p3,
    const float* __restrict__ p4, const float* __restrict__ p5,
    const float* __restrict__ p6, const float* __restrict__ p7,
    float* __restrict__ out, long long n) {
    __shared__ u16 tiles[65536];     // 2 x 32768 u16 (2 x 64KB slice buffers)

    const int bid  = blockIdx.x;
    const int tid  = threadIdx.x;
    const int wave = tid >> 6, lane = tid & 63;
    const int lr = lane & 15, quad = lane >> 4;
    const int waveM = wave >> 2, waveN = wave & 3;   // 2 x 4 wave grid
    // XCD-aware swizzle: x = XCD (bid%8), s = slot. XCD x owns an 8x4 region.
    const int x = bid & 7, s = bid >> 3;
    const int rowtile = (x >> 2) * 8 + (s >> 2);     // 0..15
    const int coltile = (x & 3) * 4 + (s & 3);       // 0..15
    const int rowBase = rowtile * 256;
    const int colBase = coltile * 256;

    // staging role: wave w stages fragments f = w*8 + j (j=0..7)
    const int sa = wave >> 1;
    const u16* gb = (sa == 0) ? Ah : (sa == 1) ? Al : (sa == 2) ? Bh : Bl;
    const int base16 = ((sa < 2) ? rowBase : colBase) >> 4;
    const int jb = (wave & 1) * 8;

#define STAGE(slice, bufb)                                                    \
    {                                                                         \
        _Pragma("unroll")                                                     \
        for (int j = 0; j < 8; j++) {                                         \
            size_t ge = ((size_t)(base16 + jb + j)) * 8192 +                  \
                        (size_t)(slice) * 512 + lane * 8;                     \
            gload16(gb + ge, &tiles[(bufb) + (wave * 8 + j) * 512]);          \
        }                                                                     \
    }

    floatx4 acc[8][4];
#pragma unroll
    for (int mi = 0; mi < 8; mi++)
#pragma unroll
        for (int ni = 0; ni < 4; ni++) acc[mi][ni] = (floatx4)0.0f;

    const int Gq = (int)((n - 3) >> 2);
    const int ni32 = (int)n;
    float* dst5 = out + 5;

    // prologue: stage slice 0 into buffer 0
    STAGE(0, 0)

    // head+tail of the 8 state arrays (tiny): block 0 only
    if (bid == 0 && tid < 32) {
        int arr = tid >> 2, j = tid & 3;
        const float* sp = (arr & 4) ? ((arr & 2) ? ((arr & 1) ? p7 : p6) : ((arr & 1) ? p5 : p4))
                                    : ((arr & 2) ? ((arr & 1) ? p3 : p2) : ((arr & 1) ? p1 : p0));
        float* dp = dst5 + (size_t)arr * (size_t)n;
        long long tail0 = 3 + 4 * (long long)Gq;
        if (j < 3) dp[j] = sp[j];
        else
            for (long long z = tail0; z < n; z++) dp[z] = sp[z];
    }
    __syncthreads();   // buffer 0 ready

#pragma unroll 1
    for (int t = 0; t < 16; t++) {
        const int cb = (t & 1) << 15;        // current buffer (u16 offset)
        const int nb = cb ^ 32768;           // next buffer
        if (t < 15) STAGE(t + 1, nb)

        // fused state-copy: loads issued here, in flight under the MFMAs
        bool docopy = false;
        float c0 = 0.f, c1 = 0.f, c2 = 0.f, c3 = 0.f;
        int cdst = 0;
        {
            int c = bid * 512 + tid + t * 131072;
            int ck = c >> 18;
            int g = c & 262143;
            if (g < Gq) {
                docopy = true;
                int ce = 3 + 4 * g;
                cdst = ck * ni32 + ce;
                const float* sp = (ck & 4) ? ((ck & 2) ? ((ck & 1) ? p7 : p6) : ((ck & 1) ? p5 : p4))
                                           : ((ck & 2) ? ((ck & 1) ? p3 : p2) : ((ck & 1) ? p1 : p0));
                c0 = sp[ce]; c1 = sp[ce + 1]; c2 = sp[ce + 2]; c3 = sp[ce + 3];
            }
        }

        // compute slice t from current buffer (single pass; acc in AGPRs)
        {
            const int ab = cb + lane * 8;
            bf16x8 bh[4], bl[4];
#pragma unroll
            for (int ni = 0; ni < 4; ni++) {
                bh[ni] = *(const bf16x8*)&tiles[ab + (32 + waveN * 4 + ni) * 512];
                bl[ni] = *(const bf16x8*)&tiles[ab + (48 + waveN * 4 + ni) * 512];
            }
#pragma unroll
            for (int mi = 0; mi < 8; mi++) {
                bf16x8 ah = *(const bf16x8*)&tiles[ab + (waveM * 8 + mi) * 512];
                bf16x8 al = *(const bf16x8*)&tiles[ab + (16 + waveM * 8 + mi) * 512];
#pragma unroll
                for (int ni = 0; ni < 4; ni++) {
                    acc[mi][ni] = __builtin_amdgcn_mfma_f32_16x16x32_bf16(ah, bh[ni], acc[mi][ni], 0, 0, 0);
                    acc[mi][ni] = __builtin_amdgcn_mfma_f32_16x16x32_bf16(ah, bl[ni], acc[mi][ni], 0, 0, 0);
                    acc[mi][ni] = __builtin_amdgcn_mfma_f32_16x16x32_bf16(al, bh[ni], acc[mi][ni], 0, 0, 0);
                }
            }
        }

        if (docopy) {
            float4 q = {c0, c1, c2, c3};
            *(float4*)&dst5[cdst] = q;
        }
        __syncthreads();   // stage(t+1) landed + all reads of cb done
    }
#undef STAGE

    // --- epilogue ---
    // C/D layout: v(rr,cc): rr = rowBase+waveM*128+mi*16+quad*4+r,
    //                       cc = colBase+waveN*64+ni*16+lr   [m89/m91]
    float* redbuf = (float*)tiles;   // rows [0,3072), cols [3072,4608)

    // diagonal capture (raw sim value). STATIC acc indices, runtime predicate.
    if (rowtile == coltile) {
#pragma unroll
        for (int mi = 0; mi < 8; mi++)
#pragma unroll
            for (int ni = 0; ni < 4; ni++) {
                if (waveM * 128 + mi * 16 != waveN * 64 + ni * 16) continue;
#pragma unroll
                for (int r = 0; r < 4; r++)
                    if (lr == quad * 4 + r)
                        diag[colBase + waveN * 64 + ni * 16 + lr] = acc[mi][ni][r];
            }
    }

    // row partials: max-first, then one exp per element
#pragma unroll
    for (int mi = 0; mi < 8; mi++) {
#pragma unroll
        for (int r = 0; r < 4; r++) {
            int row_local = waveM * 128 + mi * 16 + quad * 4 + r;
            float vmax = fmaxf(fmaxf(acc[mi][0][r], acc[mi][1][r]),
                               fmaxf(acc[mi][2][r], acc[mi][3][r]));
#pragma unroll
            for (int mask = 1; mask <= 8; mask <<= 1)
                vmax = fmaxf(vmax, __shfl_xor(vmax, mask));
            float it = 1.0f / taur[rowBase + row_local];
            float M = vmax * it;
            float P0 = 0.f, P1 = 0.f;
#pragma unroll
            for (int ni = 0; ni < 4; ni++) {
                float y = acc[mi][ni][r] * it;
                float e = __expf(y - M);
                P0 += e;
                P1 += y * e;
            }
#pragma unroll
            for (int mask = 1; mask <= 8; mask <<= 1) {
                P0 += __shfl_xor(P0, mask);
                P1 += __shfl_xor(P1, mask);
            }
            if (lr == 0) {
                int xx = (row_local * 4 + waveN) * 3;
                redbuf[xx] = M; redbuf[xx + 1] = P0; redbuf[xx + 2] = P1;
            }
        }
    }

    // col partials: max-first, then one exp per element
#pragma unroll
    for (int ni = 0; ni < 4; ni++) {
        int col_local = waveN * 64 + ni * 16 + lr;
        float vmax = -3.4e38f;
#pragma unroll
        for (int mi = 0; mi < 8; mi++)
            vmax = fmaxf(vmax,
                fmaxf(fmaxf(acc[mi][ni][0], acc[mi][ni][1]),
                      fmaxf(acc[mi][ni][2], acc[mi][ni][3])));
#pragma unroll
        for (int mask = 16; mask <= 32; mask <<= 1)
            vmax = fmaxf(vmax, __shfl_xor(vmax, mask));
        float it = 1.0f / tauc[colBase + col_local];
        float M = vmax * it;
        float P0 = 0.f, P1 = 0.f;
#pragma unroll
        for (int mi = 0; mi < 8; mi++)
#pragma unroll
            for (int r = 0; r < 4; r++) {
                float y = acc[mi][ni][r] * it;
                float e = __expf(y - M);
                P0 += e;
                P1 += y * e;
            }
#pragma unroll
        for (int mask = 16; mask <= 32; mask <<= 1) {
            P0 += __shfl_xor(P0, mask);
            P1 += __shfl_xor(P1, mask);
        }
        if (quad == 0) {
            int xx = 3072 + (col_local * 2 + waveM) * 3;
            redbuf[xx] = M; redbuf[xx + 1] = P0; redbuf[xx + 2] = P1;
        }
    }
    __syncthreads();

    if (tid < 256) {
        int xx = tid * 12;
        float M = redbuf[xx], P0 = redbuf[xx + 1], P1 = redbuf[xx + 2];
        comb(M, P0, P1, redbuf[xx + 3], redbuf[xx + 4], redbuf[xx + 5]);
        comb(M, P0, P1, redbuf[xx + 6], redbuf[xx + 7], redbuf[xx + 8]);
        comb(M, P0, P1, redbuf[xx + 9], redbuf[xx + 10], redbuf[xx + 11]);
        float* dst = &rowpart[(size_t)(rowBase + tid) * 48 + coltile * 3];
        dst[0] = M; dst[1] = P0; dst[2] = P1;
    } else {
        int c = tid - 256;
        int xx = 3072 + c * 6;
        float M = redbuf[xx], P0 = redbuf[xx + 1], P1 = redbuf[xx + 2];
        comb(M, P0, P1, redbuf[xx + 3], redbuf[xx + 4], redbuf[xx + 5]);
        float* dst = &colpart[(size_t)(colBase + c) * 48 + rowtile * 3];
        dst[0] = M; dst[1] = P0; dst[2] = P1;
    }
}

// ---------------------------------------------------------------------------
// Final per-row/col state update from partials + FUSED scalar means.
// One thread per (side,row). Partials: 12 independent float4 loads.
// Scalars: 4-wave block reduce of {lossr, tw, tau} -> 3 relaxed agent-scope
// float atomicAdds into ctrl accumulators (coherence-point ops -- no L2
// writeback fences, unlike r7's failed release-fence design); acq-rel ticket;
// 32nd block reads accumulators via fetch_add(0.0f) and writes out[0..4].
// ---------------------------------------------------------------------------
struct FinArgs {
    const float* rowpart; const float* colpart; const float* diag;
    const float* tauI; const float* sI; const float* bI; const float* uI;
    const float* tauT; const float* sT; const float* bT; const float* uT;
    const int* img_ids; const int* txt_ids; const int* epoch_p;
    float* out; u32* ctrl; long long n;
};

__global__ __launch_bounds__(256) void rows_final(FinArgs a) {
    int t = blockIdx.x * 256 + threadIdx.x;   // 8192 threads
    int side = t >> 12, i = t & 4095;         // block-uniform side
    const float* part   = side ? a.colpart : a.rowpart;
    const int*   ids    = side ? a.txt_ids : a.img_ids;
    const float* tau_in = side ? a.tauT : a.tauI;
    const float* s_in   = side ? a.sT   : a.sI;
    const float* b_in   = side ? a.bT   : a.bI;
    const float* u_in   = side ? a.uT   : a.uI;

    const int id = ids[i];                    // issue gather early
    const float dg = a.diag[i];

    const float4* p4 = (const float4*)(part + (size_t)i * 48);
    float v[48];
#pragma unroll
    for (int k = 0; k < 12; k++) {
        float4 q = p4[k];
        v[4 * k]     = q.x;
        v[4 * k + 1] = q.y;
        v[4 * k + 2] = q.z;
        v[4 * k + 3] = q.w;
    }
    float M = -3.4e38f, P0 = 0.f, P1 = 0.f;
#pragma unroll
    for (int k = 0; k < 16; k++)
        comb(M, P0, P1, v[3 * k], v[3 * k + 1], v[3 * k + 2]);

    const float tau   = tau_in[id];
    const float old_b = b_in[id];
    const float old_s = s_in[id];
    const float old_u = u_in[id];
    const float y_ii  = dg / tau;

    float b_row = fmaxf(M - y_ii, old_b);
    float e  = expf(M - y_ii - b_row);
    float S0 = P0 * e - expf(-b_row);           // mask diagonal term
    float S1 = (P1 - y_ii * P0) * e;            // diagonal contributes 0

    float g = S0;
    float sI = (*a.epoch_p == 0) ? g
             : 0.2f * old_s * expf(old_b - b_row) + 0.8f * g;
    float denom = sI + 1e-10f;
    float wsum = S1 / denom;
    float lossr = tau * wsum;
    float tw = logf(sI * (1.0f / 4095.0f)) + b_row + 8.0f - wsum;
    tw = fminf(fmaxf(tw, -5.0f), 5.0f);
    float uval = 0.5f * old_u + 0.5f * tw;
    float taun = fminf(fmaxf(tau - 1e-5f * uval, 0.005f), 0.05f);

    float* sect = a.out + 5;
    sect[(size_t)(0 + side) * (size_t)a.n + id] = sI;
    sect[(size_t)(2 + side) * (size_t)a.n + id] = b_row;
    sect[(size_t)(4 + side) * (size_t)a.n + id] = uval;
    sect[(size_t)(6 + side) * (size_t)a.n + id] = taun;

    // ---- fused scalars: block reduce {lossr, tw, tau} ----
    __shared__ float sred[4][3];
    const int lane = threadIdx.x & 63, wv = threadIdx.x >> 6;
    float r0 = lossr, r1 = tw, r2 = tau;
#pragma unroll
    for (int o = 32; o > 0; o >>= 1) {
        r0 += __shfl_xor(r0, o);
        r1 += __shfl_xor(r1, o);
        r2 += __shfl_xor(r2, o);
    }
    if (lane == 0) { sred[wv][0] = r0; sred[wv][1] = r1; sred[wv][2] = r2; }
    __syncthreads();
    if (threadIdx.x == 0) {
        float t0 = sred[0][0] + sred[1][0] + sred[2][0] + sred[3][0];
        float t1 = sred[0][1] + sred[1][1] + sred[2][1] + sred[3][1];
        float t2 = sred[0][2] + sred[1][2] + sred[2][2] + sred[3][2];
        float* accs = (float*)a.ctrl;   // [loss,tw,tau] x {I,T}; ticket at [6]
        __hip_atomic_fetch_add(&accs[side * 3 + 0], t0, __ATOMIC_RELAXED,
                               __HIP_MEMORY_SCOPE_AGENT);
        __hip_atomic_fetch_add(&accs[side * 3 + 1], t1, __ATOMIC_RELAXED,
                               __HIP_MEMORY_SCOPE_AGENT);
        __hip_atomic_fetch_add(&accs[side * 3 + 2], t2, __ATOMIC_RELAXED,
                               __HIP_MEMORY_SCOPE_AGENT);
        u32 tk = __hip_atomic_fetch_add(&a.ctrl[6], 1u, __ATOMIC_ACQ_REL,
                                        __HIP_MEMORY_SCOPE_AGENT);
        if (tk == 31u) {
            float s0 = __hip_atomic_fetch_add(&accs[0], 0.0f, __ATOMIC_RELAXED, __HIP_MEMORY_SCOPE_AGENT);
            float s1 = __hip_atomic_fetch_add(&accs[1], 0.0f, __ATOMIC_RELAXED, __HIP_MEMORY_SCOPE_AGENT);
            float s2 = __hip_atomic_fetch_add(&accs[2], 0.0f, __ATOMIC_RELAXED, __HIP_MEMORY_SCOPE_AGENT);
            float s3 = __hip_atomic_fetch_add(&accs[3], 0.0f, __ATOMIC_RELAXED, __HIP_MEMORY_SCOPE_AGENT);
            float s4 = __hip_atomic_fetch_add(&accs[4], 0.0f, __ATOMIC_RELAXED, __HIP_MEMORY_SCOPE_AGENT);
            float s5 = __hip_atomic_fetch_add(&accs[5], 0.0f, __ATOMIC_RELAXED, __HIP_MEMORY_SCOPE_AGENT);
            const float inv = 1.0f / 4096.0f;
            a.out[0] = (s0 + s3) * inv;   // total loss
            a.out[1] = s2 * inv;          // tau_img mean
            a.out[2] = s5 * inv;          // tau_txt mean
            a.out[3] = s1 * inv;          // tw_i mean
            a.out[4] = s4 * inv;          // tw_t mean
        }
    }
}

extern "C" void kernel_launch(void* const* d_in, const int* in_sizes, int n_in,
                              void* d_out, int out_size, void* d_ws, size_t ws_size,
                              hipStream_t stream) {
    const float* img   = (const float*)d_in[0];
    const float* txt   = (const float*)d_in[1];
    const float* s_I   = (const float*)d_in[2];
    const float* s_T   = (const float*)d_in[3];
    const float* b_I   = (const float*)d_in[4];
    const float* b_T   = (const float*)d_in[5];
    const float* u_I   = (const float*)d_in[6];
    const float* u_T   = (const float*)d_in[7];
    const float* tau_I = (const float*)d_in[8];
    const float* tau_T = (const float*)d_in[9];
    const int* image_ids = (const int*)d_in[10];
    const int* text_ids  = (const int*)d_in[11];
    const int* epoch     = (const int*)d_in[12];
    float* out = (float*)d_out;
    const long long n = in_sizes[2];   // 1,000,000
    const int nfeat = in_sizes[0];     // 4096*512

    const size_t MB = 1024 * 1024;
    // ws layout (< 24MB):
    //  [0,16MB): fragment-major splits Ah/Al/Bh/Bl
    //  16MB: rowpart 4096x16x3 f32 | 18MB: colpart | 20MB: diag
    //  20.25MB: taur | 20.5MB: tauc | 22MB: ctrl (6 f32 accs + ticket)
    u16* Ah = (u16*)d_ws;
    u16* Al = Ah + (size_t)nfeat;
    u16* Bh = Al + (size_t)nfeat;
    u16* Bl = Bh + (size_t)nfeat;
    float* rowpart = (float*)((char*)d_ws + 16 * MB);
    float* colpart = (float*)((char*)d_ws + 18 * MB);
    float* diag    = (float*)((char*)d_ws + 20 * MB);
    float* taur    = (float*)((char*)d_ws + 20 * MB + 256 * 1024);
    float* tauc    = (float*)((char*)d_ws + 20 * MB + 512 * 1024);
    u32*   ctrl    = (u32*)((char*)d_ws + 22 * MB);

    presplit<<<dim3((nfeat / 8 + 255) / 256, 2), 256, 0, stream>>>(
        img, txt, Ah, Al, Bh, Bl, nfeat,
        tau_I, tau_T, image_ids, text_ids, taur, tauc, ctrl);

    gemm_flash<<<256, 512, 0, stream>>>(
        Ah, Al, Bh, Bl, taur, tauc, rowpart, colpart, diag,
        s_I, s_T, b_I, b_T, u_I, u_T, tau_I, tau_T, out, n);

    FinArgs fa;
    fa.rowpart = rowpart; fa.colpart = colpart; fa.diag = diag;
    fa.tauI = tau_I; fa.sI = s_I; fa.bI = b_I; fa.uI = u_I;
    fa.tauT = tau_T; fa.sT = s_T; fa.bT = b_T; fa.uT = u_T;
    fa.img_ids = image_ids; fa.txt_ids = text_ids; fa.epoch_p = epoch;
    fa.out = out; fa.ctrl = ctrl; fa.n = n;
    rows_final<<<32, 256, 0, stream>>>(fa);
}